// Round 9
// baseline (37.721 us; speedup 1.0000x reference)
//
#include <hip/hip_runtime.h>
#include <math.h>

#define NB 32
#define NT 128
#define KD 16

typedef float f32x4 __attribute__((ext_vector_type(4)));
typedef short bf16x8 __attribute__((ext_vector_type(8)));
typedef __fp16 f16x2 __attribute__((ext_vector_type(2)));
union U4B8 { uint4 u; bf16x8 h; };
union U4H8 { uint4 u; f16x2 h[4]; };

// LDS byte map (82688 B total, 1 block/CU)
#define L_PK 0        // f32 [128][68] = 34816 ; aliased by H1/H2 after sync2
#define L_PV 34816    // f16 [64][136] = 17408
#define L_P  52224    // f16 [64][136] = 17408 (p~ rows)
#define L_Q  69632    // f32 [16][68]  = 4352
#define L_S  73984    // f32 [128][17] = 8704 ; aliased by X bf16 [16][104] post-sync1
#define L_X  73984
#define L_TOT 82688
#define L_H1 0        // bf16 [16][264] = 8448
#define L_H2 8448     // ends 16896 < 34816

__device__ __forceinline__ unsigned short bf16rne(float f) {
    unsigned u = __float_as_uint(f);
    return (unsigned short)((u + 0x7fffu + ((u >> 16) & 1u)) >> 16);
}
__device__ __forceinline__ unsigned cvt2bf(float a, float b) {
    unsigned r;
    asm("v_cvt_pk_bf16_f32 %0, %1, %2" : "=v"(r) : "v"(a), "v"(b));
    return r;   // lo16 = bf16(a), hi16 = bf16(b)
}
__device__ __forceinline__ void unpack8(uint4 u, float* f) {
    f[0] = __uint_as_float(u.x << 16); f[1] = __uint_as_float(u.x & 0xffff0000u);
    f[2] = __uint_as_float(u.y << 16); f[3] = __uint_as_float(u.y & 0xffff0000u);
    f[4] = __uint_as_float(u.z << 16); f[5] = __uint_as_float(u.z & 0xffff0000u);
    f[6] = __uint_as_float(u.w << 16); f[7] = __uint_as_float(u.w & 0xffff0000u);
}
__device__ __forceinline__ f16x2 pkmax(f16x2 a, f16x2 b) {
    f16x2 d;
    asm("v_pk_max_f16 %0, %1, %2" : "=v"(d) : "v"(a), "v"(b));
    return d;
}
#if __has_builtin(__builtin_amdgcn_fdot2)
#define FDOT2(a, b, c) __builtin_amdgcn_fdot2((a), (b), (c), false)
#else
#define FDOT2(a, b, c) ((c) + (float)(a)[0] * (float)(b)[0] + (float)(a)[1] * (float)(b)[1])
#endif

__global__ __launch_bounds__(1024, 4) void actor_kernel(
    const float* __restrict__ state, const float* __restrict__ eps,
    const float* __restrict__ Wq, const float* __restrict__ bq,
    const float* __restrict__ Wk, const float* __restrict__ bk,
    const float* __restrict__ Wv, const float* __restrict__ bv,
    const float* __restrict__ W1, const float* __restrict__ b1g,
    const float* __restrict__ W2, const float* __restrict__ b2g,
    const float* __restrict__ Wmu, const float* __restrict__ bmu,
    const float* __restrict__ Wls, const float* __restrict__ bls,
    float* __restrict__ out)
{
    __shared__ __align__(16) char sm[L_TOT];
    float* smS  = (float*)(sm + L_S);
    float* smQ  = (float*)(sm + L_Q);
    float* smPk = (float*)(sm + L_PK);

    const int tid = threadIdx.x, w = tid >> 6, lane = tid & 63;
    const int b = blockIdx.x >> 3, tile = blockIdx.x & 7;
    const int iloc = tile * 16 + w;                 // this wave's row in batch
    const int h = lane >> 4, s = lane & 15, h16 = h << 4;
    const int g = h, lr = s;                        // MFMA frag coords
    const int n1 = w * 16 + lr;                     // this wave's neuron column

    // ---- stage state[b] into LDS f32 [128][17]; prefetch X-tail ----
    if (tid < 512) {
        float4 v = ((const float4*)(state + (size_t)b * NT * KD))[tid];
        int r = tid >> 2, c = (tid & 3) * 4;
        float* dst = smS + r * 17 + c;
        dst[0] = v.x; dst[1] = v.y; dst[2] = v.z; dst[3] = v.w;
    }
    float stt = 0.f;
    if (tid < 256)
        stt = state[((size_t)b * NT + tile * 16 + (tid >> 4)) * KD + (tid & 15)];

    // per-lane projection weight columns (o = lane), die after phase 1
    float wqv[16], wkv[16], wvv[16];
    {
        const float4* q4 = (const float4*)(Wq + lane * KD);
        const float4* k4 = (const float4*)(Wk + lane * KD);
        const float4* v4 = (const float4*)(Wv + lane * KD);
        #pragma unroll
        for (int r4 = 0; r4 < 4; ++r4) {
            float4 a = q4[r4], c = k4[r4], d = v4[r4];
            wqv[r4*4+0]=a.x; wqv[r4*4+1]=a.y; wqv[r4*4+2]=a.z; wqv[r4*4+3]=a.w;
            wkv[r4*4+0]=c.x; wkv[r4*4+1]=c.y; wkv[r4*4+2]=c.z; wkv[r4*4+3]=c.w;
            wvv[r4*4+0]=d.x; wvv[r4*4+1]=d.y; wvv[r4*4+2]=d.z; wvv[r4*4+3]=d.w;
        }
    }
    const float bqo = bq[lane], bvo = bv[lane];
    __syncthreads();   // sync0: smS ready

    // ---- phase 1: Q (own row), Pk f32 + Pv f16 (8 j-rows per wave) ----
    {
        const float* sr = smS + iloc * 17;
        float aq = bqo;
        #pragma unroll
        for (int m = 0; m < 16; ++m) aq = fmaf(sr[m], wqv[m], aq);
        smQ[w * 68 + lane] = fmaxf(aq, 0.f) * 0.25f;   // 1/sqrt(16) folded
    }
    {
        float av[8];
        #pragma unroll
        for (int r = 0; r < 8; ++r) {
            const float* sr = smS + (w * 8 + r) * 17;   // broadcast reads
            float ak = 0.f, vv = 0.f;
            #pragma unroll
            for (int m = 0; m < 16; ++m) {
                ak = fmaf(sr[m], wkv[m], ak);
                vv = fmaf(sr[m], wvv[m], vv);
            }
            smPk[(w * 8 + r) * 68 + lane] = ak;
            av[r] = vv;
        }
        U4H8 pv;
        pv.h[0] = __builtin_amdgcn_cvt_pkrtz(av[0], av[1]);
        pv.h[1] = __builtin_amdgcn_cvt_pkrtz(av[2], av[3]);
        pv.h[2] = __builtin_amdgcn_cvt_pkrtz(av[4], av[5]);
        pv.h[3] = __builtin_amdgcn_cvt_pkrtz(av[6], av[7]);
        *(uint4*)(sm + L_PV + lane * 272 + w * 16) = pv.u;   // [o][j] f16
    }
    __syncthreads();   // sync1: smQ / smPk / smPv ready

    // ---- per-row constants: relu(x+c) = c + max(x,-c); sum_j p_j = 1 ----
    float q[16], mbeff[16], dotc = 0.f;
    {
        const float* qrow = smQ + w * 68 + h16;      // broadcast
        const float* pkI  = smPk + iloc * 68 + h16;  // broadcast
        const float4* bk4 = (const float4*)(bk + h16);
        #pragma unroll
        for (int q4 = 0; q4 < 4; ++q4) {
            float4 bb = bk4[q4];
            float bbv[4] = {bb.x, bb.y, bb.z, bb.w};
            #pragma unroll
            for (int kk = 0; kk < 4; ++kk) {
                int k = q4 * 4 + kk;
                float qv = qrow[k], pk = pkI[k];
                q[k] = qv;
                mbeff[k] = pk - bbv[kk];                 // -c
                dotc = fmaf(qv, bbv[kk] - pk, dotc);     // + sum q*c
            }
        }
    }

    // ---- scores f32: lane (h,s) covers j = s + 16*jj ----
    float sc[8];
    #pragma unroll
    for (int jj = 0; jj < 8; ++jj) {
        const float4* pk = (const float4*)(smPk + (s + (jj << 4)) * 68 + h16);
        float a = dotc;
        #pragma unroll
        for (int q4 = 0; q4 < 4; ++q4) {
            float4 v = pk[q4];
            float f[4] = {v.x, v.y, v.z, v.w};
            #pragma unroll
            for (int kk = 0; kk < 4; ++kk) {
                int k = q4 * 4 + kk;
                a = fmaf(q[k], fmaxf(f[kk], mbeff[k]), a);
            }
        }
        sc[jj] = a;
    }

    // ---- softmax over 128 j within the 16-lane head group ----
    float mx = sc[0];
    #pragma unroll
    for (int jj = 1; jj < 8; ++jj) mx = fmaxf(mx, sc[jj]);
    #pragma unroll
    for (int off = 1; off < 16; off <<= 1) mx = fmaxf(mx, __shfl_xor(mx, off));
    float l = 0.f;
    #pragma unroll
    for (int jj = 0; jj < 8; ++jj) { sc[jj] = __expf(sc[jj] - mx); l += sc[jj]; }
    #pragma unroll
    for (int off = 1; off < 16; off <<= 1) l += __shfl_xor(l, off);
    const float rl = 1.0f / l;
    {
        __fp16* prow = (__fp16*)(sm + L_P) + (w * 4 + h) * 136;
        #pragma unroll
        for (int jj = 0; jj < 8; ++jj) prow[(jj << 4) + s] = (__fp16)sc[jj];
    }
    // issue W1 raw loads now: latency hides under PV (24 transient VGPRs)
    float4 w1lo[3], w1hi[3];
    #pragma unroll
    for (int ks = 0; ks < 3; ++ks) {
        int kb = ks * 32 + g * 8;
        if (kb < 80) {
            w1lo[ks] = *(const float4*)(W1 + n1 * 80 + kb);
            w1hi[ks] = *(const float4*)(W1 + n1 * 80 + kb + 4);
        }
    }
    asm volatile("s_waitcnt lgkmcnt(0)" ::: "memory");
    __builtin_amdgcn_sched_barrier(0);

    // ---- PV packed f16: x = -mbv + rl * sum p~ * max(v, mbv) ----
    float xA;
    {
        const __fp16 pvi = *((const __fp16*)(sm + L_PV) + lane * 136 + iloc);
        const float mbvf = (float)pvi - bvo;
        const __fp16 mbvh = (__fp16)mbvf;
        const f16x2 mbv2 = {mbvh, mbvh};
        const uint4* vrow = (const uint4*)(sm + L_PV + lane * 272);
        const uint4* prow = (const uint4*)(sm + L_P + (w * 4 + h) * 272);
        float acc = 0.f;
        #pragma unroll
        for (int u = 0; u < 16; ++u) {
            U4H8 v; v.u = vrow[u];
            U4H8 p; p.u = prow[u];
            #pragma unroll
            for (int t = 0; t < 4; ++t)
                acc = FDOT2(p.h[t], pkmax(v.h[t], mbv2), acc);
        }
        xA = fmaf(rl, acc, -(float)mbvh);
    }

    // convert W1 frags (loads have landed during PV)
    uint4 w1f[3];
    #pragma unroll
    for (int ks = 0; ks < 3; ++ks) {
        int kb = ks * 32 + g * 8;
        if (kb < 80) {
            w1f[ks].x = cvt2bf(w1lo[ks].x, w1lo[ks].y);
            w1f[ks].y = cvt2bf(w1lo[ks].z, w1lo[ks].w);
            w1f[ks].z = cvt2bf(w1hi[ks].x, w1hi[ks].y);
            w1f[ks].w = cvt2bf(w1hi[ks].z, w1hi[ks].w);
        } else {
            w1f[ks] = make_uint4(0, 0, 0, 0);
        }
    }

    // ---- X tile bf16 [16][104] (aliases smS; all smS reads were pre-sync1) ----
    ((unsigned short*)(sm + L_X))[w * 104 + lane] = bf16rne(xA);
    if (tid < 256) {
        unsigned short* xr = (unsigned short*)(sm + L_X) + (tid >> 4) * 104;
        xr[64 + (tid & 15)] = bf16rne(stt);
        xr[80 + (tid & 15)] = 0;
    }
    __syncthreads();   // sync2: X ready; Pk reads all done -> H1/H2 alias safe

    // ---- layer 1 MFMA (K=96): wave w -> neurons w*16..w*16+15 ----
    // prefetch W2 ks=0 so its latency hides under L1
    const float4* w2p = (const float4*)(W2 + n1 * 256 + g * 8);
    float4 w2lo = w2p[0], w2hi = w2p[1];
    {
        f32x4 a1 = {0.f, 0.f, 0.f, 0.f};
        #pragma unroll
        for (int ks = 0; ks < 3; ++ks) {
            U4B8 av; av.u = *(const uint4*)(sm + L_X + (lr * 104 + ks * 32 + g * 8) * 2);
            U4B8 bw; bw.u = w1f[ks];
            a1 = __builtin_amdgcn_mfma_f32_16x16x32_bf16(av.h, bw.h, a1, 0, 0, 0);
        }
        const float bn = b1g[n1];
        #pragma unroll
        for (int qq = 0; qq < 4; ++qq)
            *((unsigned short*)(sm + L_H1) + (4 * g + qq) * 264 + n1) =
                bf16rne(fmaxf(a1[qq] + bn, 0.f));
    }
    __syncthreads();   // sync3

    // ---- layer 2 MFMA (K=256), in-loop load+cvt with 1-ahead prefetch ----
    {
        f32x4 a2 = {0.f, 0.f, 0.f, 0.f};
        #pragma unroll 1
        for (int ks = 0; ks < 8; ++ks) {
            float4 nlo, nhi;
            if (ks < 7) { nlo = w2p[(ks + 1) * 8]; nhi = w2p[(ks + 1) * 8 + 1]; }
            U4B8 bw;
            bw.u.x = cvt2bf(w2lo.x, w2lo.y);
            bw.u.y = cvt2bf(w2lo.z, w2lo.w);
            bw.u.z = cvt2bf(w2hi.x, w2hi.y);
            bw.u.w = cvt2bf(w2hi.z, w2hi.w);
            U4B8 av; av.u = *(const uint4*)(sm + L_H1 + (lr * 264 + ks * 32 + g * 8) * 2);
            a2 = __builtin_amdgcn_mfma_f32_16x16x32_bf16(av.h, bw.h, a2, 0, 0, 0);
            w2lo = nlo; w2hi = nhi;
        }
        const float bn = b2g[n1];
        #pragma unroll
        for (int qq = 0; qq < 4; ++qq)
            *((unsigned short*)(sm + L_H2) + (4 * g + qq) * 264 + n1) =
                bf16rne(fmaxf(a2[qq] + bn, 0.f));
    }
    __syncthreads();   // sync4

    // ---- heads + finalize (first 256 threads: row m, k-slice cc) ----
    if (tid < 256) {
        const int m = tid >> 4, cc = tid & 15;
        float hbuf[16];
        uint4 ha = *(const uint4*)(sm + L_H2 + (m * 264 + cc * 16) * 2);
        uint4 hb = *(const uint4*)(sm + L_H2 + (m * 264 + cc * 16 + 8) * 2);
        unpack8(ha, hbuf); unpack8(hb, hbuf + 8);
        float d0 = 0.f, d1 = 0.f, d2 = 0.f, d3 = 0.f;
        #pragma unroll
        for (int kk = 0; kk < 16; ++kk) {
            int k = cc * 16 + kk;
            float hv = hbuf[kk];
            d0 = fmaf(hv, Wmu[k], d0);
            d1 = fmaf(hv, Wmu[256 + k], d1);
            d2 = fmaf(hv, Wls[k], d2);
            d3 = fmaf(hv, Wls[256 + k], d3);
        }
        #pragma unroll
        for (int off = 1; off < 16; off <<= 1) {
            d0 += __shfl_xor(d0, off);
            d1 += __shfl_xor(d1, off);
            d2 += __shfl_xor(d2, off);
            d3 += __shfl_xor(d3, off);
        }
        if (cc == 0) {
            const int orow = b * NT + tile * 16 + m;
            float mu0 = tanhf(d0 + bmu[0]);
            float mu1 = tanhf(d1 + bmu[1]);
            float t2  = tanhf(d2 + bls[0]);
            float t3  = tanhf(d3 + bls[1]);
            float ls0 = -20.f + 11.f * (t2 + 1.f);
            float ls1 = -20.f + 11.f * (t3 + 1.f);
            float e0 = eps[orow * 2], e1 = eps[orow * 2 + 1];
            float z0 = mu0 + __expf(ls0) * e0;
            float z1 = mu1 + __expf(ls1) * e1;
            float a0 = tanhf(z0), a1 = tanhf(z1);
            out[orow * 2]     = a0;
            out[orow * 2 + 1] = a1;
            float lp = -0.5f * e0 * e0 - ls0 - 0.91893853320467274f - __logf(1.f - a0 * a0 + 1e-7f)
                     + -0.5f * e1 * e1 - ls1 - 0.91893853320467274f - __logf(1.f - a1 * a1 + 1e-7f);
            out[NB * NT * 2 + orow] = lp;
        }
    }
}

extern "C" void kernel_launch(void* const* d_in, const int* in_sizes, int n_in,
                              void* d_out, int out_size, void* d_ws, size_t ws_size,
                              hipStream_t stream) {
    const float* state = (const float*)d_in[0];
    const float* eps   = (const float*)d_in[1];
    const float* Wq    = (const float*)d_in[2];
    const float* bq    = (const float*)d_in[3];
    const float* Wk    = (const float*)d_in[4];
    const float* bk    = (const float*)d_in[5];
    const float* Wv    = (const float*)d_in[6];
    const float* bv    = (const float*)d_in[7];
    const float* W1    = (const float*)d_in[8];
    const float* b1    = (const float*)d_in[9];
    const float* W2    = (const float*)d_in[10];
    const float* b2    = (const float*)d_in[11];
    const float* Wmu   = (const float*)d_in[12];
    const float* bmu   = (const float*)d_in[13];
    const float* Wls   = (const float*)d_in[14];
    const float* bls   = (const float*)d_in[15];
    float* out = (float*)d_out;
    (void)d_ws; (void)ws_size;

    actor_kernel<<<NB * 8, 1024, 0, stream>>>(
        state, eps, Wq, bq, Wk, bk, Wv, bv, W1, b1, W2, b2,
        Wmu, bmu, Wls, bls, out);
}

// Round 10
// 22.765 us; speedup vs baseline: 1.6569x; 1.6569x over previous
//
#include <hip/hip_runtime.h>
#include <math.h>

#define NB 32
#define NT 128
#define KD 16

// ws byte offsets
#define QG_OFF   0u          // f32 [4096][64]    1 MB   (relu(q)*0.25)
#define PKF_OFF  1048576u    // f32 [32][128][64] 2 MB
#define PVT_OFF  3145728u    // f16 [32][64][128] 512 KB (o-major)
#define W1P_OFF  3670016u    // bf16 MFMA frags [3*16][64] uint4, 48 KB
#define W2P_OFF  3719168u    // bf16 MFMA frags [8*16][64] uint4, 128 KB

typedef float f32x4 __attribute__((ext_vector_type(4)));
typedef short bf16x8 __attribute__((ext_vector_type(8)));
typedef __fp16 f16x2 __attribute__((ext_vector_type(2)));
union U4B8 { uint4 u; bf16x8 h; };
union U4H8 { uint4 u; f16x2 h[4]; };

// actor LDS map (60928 B -> 2 blocks/CU)
#define L_PK 0        // f32 [128][68] = 34816 ; aliased by X/H1/H2 after PV
#define L_PV 34816    // f16 [64][136] = 17408 (ends 52224)
#define L_P  52224    // f16 [32][136] = 8704  (ends 60928)
#define L_TOT 60928
#define L_X  0        // bf16 [16][104] = 3328
#define L_H1 3584     // bf16 [16][264] = 8448 (ends 12032)
#define L_H2 12032    // bf16 [16][264] = 8448 (ends 20480 < 34816: Pk/Pv dead)

__device__ __forceinline__ unsigned short bf16rne(float f) {
    unsigned u = __float_as_uint(f);
    return (unsigned short)((u + 0x7fffu + ((u >> 16) & 1u)) >> 16);
}
__device__ __forceinline__ void unpack8(uint4 u, float* f) {
    f[0] = __uint_as_float(u.x << 16); f[1] = __uint_as_float(u.x & 0xffff0000u);
    f[2] = __uint_as_float(u.y << 16); f[3] = __uint_as_float(u.y & 0xffff0000u);
    f[4] = __uint_as_float(u.z << 16); f[5] = __uint_as_float(u.z & 0xffff0000u);
    f[6] = __uint_as_float(u.w << 16); f[7] = __uint_as_float(u.w & 0xffff0000u);
}
__device__ __forceinline__ f16x2 pkmax(f16x2 a, f16x2 b) {
    f16x2 d;
    asm("v_pk_max_f16 %0, %1, %2" : "=v"(d) : "v"(a), "v"(b));
    return d;
}
#if __has_builtin(__builtin_amdgcn_fdot2)
#define FDOT2(a, b, c) __builtin_amdgcn_fdot2((a), (b), (c), false)
#else
#define FDOT2(a, b, c) ((c) + (float)(a)[0] * (float)(b)[0] + (float)(a)[1] * (float)(b)[1])
#endif

// ---------------- K0: projections + MFMA weight packing (R8-proven, verbatim) ----------------
__global__ __launch_bounds__(256) void prep_kernel(
    const float* __restrict__ state,
    const float* __restrict__ Wq, const float* __restrict__ bq,
    const float* __restrict__ Wk, const float* __restrict__ Wv,
    const float* __restrict__ W1, const float* __restrict__ W2,
    char* __restrict__ wsb)
{
    const int blk = blockIdx.x, tid = threadIdx.x;
    float* Qg  = (float*)(wsb + QG_OFF);
    float* PkF = (float*)(wsb + PKF_OFF);
    unsigned short* PvT = (unsigned short*)(wsb + PVT_OFF);

    if (blk < 128) {
        __shared__ float Wl[3][64][17];
        __shared__ float Sl[32][17];
        const int b = blk >> 2, r0 = (blk & 3) * 32;
        for (int idx = tid; idx < 1024; idx += 256) {
            int o = idx >> 4, m = idx & 15;
            Wl[0][o][m] = Wq[idx];
            Wl[1][o][m] = Wk[idx];
            Wl[2][o][m] = Wv[idx];
        }
        for (int idx = tid; idx < 512; idx += 256)
            Sl[idx >> 4][idx & 15] = state[(size_t)(b * NT + r0) * KD + idx];
        __syncthreads();
        const int o = tid & 63, rr = tid >> 6;
        float wqv[16], wkv[16], wvv[16];
        #pragma unroll
        for (int m = 0; m < 16; ++m) {
            wqv[m] = Wl[0][o][m]; wkv[m] = Wl[1][o][m]; wvv[m] = Wl[2][o][m];
        }
        const float bqo = bq[o];
        for (int r = rr; r < 32; r += 4) {
            float aq = bqo, ak = 0.f, av = 0.f;
            #pragma unroll
            for (int m = 0; m < 16; ++m) {
                float s = Sl[r][m];
                aq = fmaf(s, wqv[m], aq);
                ak = fmaf(s, wkv[m], ak);
                av = fmaf(s, wvv[m], av);
            }
            int row = b * NT + r0 + r;
            Qg[row * 64 + o]  = fmaxf(aq, 0.f) * 0.25f;   // 1/sqrt(16) folded
            PkF[row * 64 + o] = ak;
            __fp16 hv = (__fp16)av;
            PvT[b * 8192 + o * NT + (r0 + r)] = *(unsigned short*)&hv;
        }
    } else if (blk < 140) {
        int fi = (blk - 128) * 256 + tid;
        int l = fi & 63, rest = fi >> 6;
        int t = rest & 15, ks = rest >> 4;
        int n = t * 16 + (l & 15);
        int kb = ks * 32 + (l >> 4) * 8;
        unsigned short v[8];
        #pragma unroll
        for (int j = 0; j < 8; ++j) {
            int k = kb + j;
            v[j] = (k < 80) ? bf16rne(W1[n * 80 + k]) : (unsigned short)0;
        }
        uint4 u;
        u.x = (unsigned)v[0] | ((unsigned)v[1] << 16);
        u.y = (unsigned)v[2] | ((unsigned)v[3] << 16);
        u.z = (unsigned)v[4] | ((unsigned)v[5] << 16);
        u.w = (unsigned)v[6] | ((unsigned)v[7] << 16);
        ((uint4*)(wsb + W1P_OFF))[fi] = u;
    } else {
        int fi = (blk - 140) * 256 + tid;
        int l = fi & 63, rest = fi >> 6;
        int t = rest & 15, ks = rest >> 4;
        int n = t * 16 + (l & 15);
        int kb = ks * 32 + (l >> 4) * 8;
        unsigned short v[8];
        #pragma unroll
        for (int j = 0; j < 8; ++j) v[j] = bf16rne(W2[n * 256 + kb + j]);
        uint4 u;
        u.x = (unsigned)v[0] | ((unsigned)v[1] << 16);
        u.y = (unsigned)v[2] | ((unsigned)v[3] << 16);
        u.z = (unsigned)v[4] | ((unsigned)v[5] << 16);
        u.w = (unsigned)v[6] | ((unsigned)v[7] << 16);
        ((uint4*)(wsb + W2P_OFF))[fi] = u;
    }
}

// ---------------- K1: 8 rows/block, 512 blocks, 2 blocks/CU ----------------
__global__ __launch_bounds__(512, 4) void actor_kernel(
    const float* __restrict__ state, const float* __restrict__ eps,
    const float* __restrict__ bkg, const float* __restrict__ bvg,
    const float* __restrict__ b1g, const float* __restrict__ b2g,
    const float* __restrict__ Wmu, const float* __restrict__ bmu,
    const float* __restrict__ Wls, const float* __restrict__ bls,
    const char* __restrict__ wsb, float* __restrict__ out)
{
    __shared__ __align__(16) char sm[L_TOT];
    float* smPk = (float*)(sm + L_PK);

    const int tid = threadIdx.x, w = tid >> 6, lane = tid & 63;
    const int bid = blockIdx.x;
    const int b    = (bid & 7) * 4 + ((bid >> 3) >> 4);  // batch -> fixed XCD
    const int tile = (bid >> 3) & 15;
    const int iloc = tile * 8 + w;                       // this wave's row in batch
    const int row  = b * NT + iloc;
    const int h = lane >> 4, s = lane & 15, h16 = h << 4;
    const int g = h, lr = s;                             // MFMA frag coords
    const int t0 = 2 * w;                                // wave's 2 neuron cols
    const int n0 = w * 32 + lr, n1 = n0 + 16;

    const float* Qg  = (const float*)(wsb + QG_OFF);
    const float* PkF = (const float*)(wsb + PKF_OFF);

    // ---- global prefetches (q, bk) overlap LDS staging ----
    float qA[16], bkr[16];
    {
        const float4* qa  = (const float4*)(Qg + (size_t)row * 64 + h16);
        const float4* bk4 = (const float4*)(bkg + h16);
        #pragma unroll
        for (int q4 = 0; q4 < 4; ++q4) {
            float4 a = qa[q4], k4 = bk4[q4];
            qA[q4*4+0]=a.x; qA[q4*4+1]=a.y; qA[q4*4+2]=a.z; qA[q4*4+3]=a.w;
            bkr[q4*4+0]=k4.x; bkr[q4*4+1]=k4.y; bkr[q4*4+2]=k4.z; bkr[q4*4+3]=k4.w;
        }
    }
    const float bvo = bvg[lane];
    float stt = 0.f;
    if (tid < 128)
        stt = state[((size_t)b * NT + tile * 8 + (tid >> 4)) * KD + (tid & 15)];

    // ---- stage Pk f32 [128][68] and Pv f16 [64][136] (R8 patterns) ----
    {
        const uint4* srcK = (const uint4*)(PkF + (size_t)b * NT * 64);   // 2048 uint4
        #pragma unroll
        for (int it = 0; it < 4; ++it) {
            int idx = tid + it * 512;
            int r = idx >> 4, c = idx & 15;
            *(uint4*)(smPk + r * 68 + c * 4) = srcK[idx];
        }
        const uint4* srcV = (const uint4*)(wsb + PVT_OFF) + (size_t)b * 1024; // 1024 uint4
        #pragma unroll
        for (int it = 0; it < 2; ++it) {
            int idx = tid + it * 512;
            int o = idx >> 4, c = idx & 15;
            *(uint4*)(sm + L_PV + o * 272 + c * 16) = srcV[idx];
        }
    }
    __syncthreads();

    // ---- per-row constants: relu(x+c) = c + max(x,-c); sum_j p_j = 1 ----
    float mbeff[16], dotc = 0.f;
    {
        const float* pkI = smPk + iloc * 68 + h16;   // broadcast
        #pragma unroll
        for (int k = 0; k < 16; ++k) {
            float pk = pkI[k];
            mbeff[k] = pk - bkr[k];                  // -c
            dotc = fmaf(qA[k], bkr[k] - pk, dotc);   // + sum q*c
        }
    }

    // ---- scores f32: lane (h,s) covers j = s + 16*jj ----
    float sc[8];
    #pragma unroll
    for (int jj = 0; jj < 8; ++jj) {
        const float4* pk = (const float4*)(smPk + (s + (jj << 4)) * 68 + h16);
        float a = dotc;
        #pragma unroll
        for (int q4 = 0; q4 < 4; ++q4) {
            float4 v = pk[q4];
            float f[4] = {v.x, v.y, v.z, v.w};
            #pragma unroll
            for (int kk = 0; kk < 4; ++kk) {
                int k = q4 * 4 + kk;
                a = fmaf(qA[k], fmaxf(f[kk], mbeff[k]), a);
            }
        }
        sc[jj] = a;
    }

    // ---- softmax over 128 j within the 16-lane head group ----
    float mx = sc[0];
    #pragma unroll
    for (int jj = 1; jj < 8; ++jj) mx = fmaxf(mx, sc[jj]);
    #pragma unroll
    for (int off = 1; off < 16; off <<= 1) mx = fmaxf(mx, __shfl_xor(mx, off));
    float l = 0.f;
    #pragma unroll
    for (int jj = 0; jj < 8; ++jj) { sc[jj] = __expf(sc[jj] - mx); l += sc[jj]; }
    #pragma unroll
    for (int off = 1; off < 16; off <<= 1) l += __shfl_xor(l, off);
    const float rl = 1.0f / l;
    {
        __fp16* prow = (__fp16*)(sm + L_P) + (w * 4 + h) * 136;
        #pragma unroll
        for (int jj = 0; jj < 8; ++jj) prow[(jj << 4) + s] = (__fp16)sc[jj];
    }
    asm volatile("s_waitcnt lgkmcnt(0)" ::: "memory");   // P row is intra-wave
    __builtin_amdgcn_sched_barrier(0);

    // ---- PV packed f16: x = -mbv + rl * sum p~ * max(v, mbv) ----
    float xA;
    {
        const __fp16 pvi = *((const __fp16*)(sm + L_PV) + lane * 136 + iloc);
        const float mbvf = (float)pvi - bvo;
        const __fp16 mbvh = (__fp16)mbvf;
        const f16x2 mbv2 = {mbvh, mbvh};
        const uint4* vrow = (const uint4*)(sm + L_PV + lane * 272);
        const uint4* prow = (const uint4*)(sm + L_P + (w * 4 + h) * 272);
        float acc = 0.f;
        #pragma unroll
        for (int u = 0; u < 16; ++u) {
            U4H8 v; v.u = vrow[u];
            U4H8 p; p.u = prow[u];
            #pragma unroll
            for (int t = 0; t < 4; ++t)
                acc = FDOT2(p.h[t], pkmax(v.h[t], mbv2), acc);
        }
        xA = fmaf(rl, acc, -(float)mbvh);
    }
    __syncthreads();   // all Pk/Pv/P reads done -> safe to alias

    // ---- X tile bf16 [16][104]: rows 0..7 live, rows 8..15 zero ----
    ((unsigned short*)(sm + L_X))[w * 104 + lane] = bf16rne(xA);
    if (tid < 128) {
        unsigned short* xr = (unsigned short*)(sm + L_X) + (tid >> 4) * 104;
        xr[64 + (tid & 15)] = bf16rne(stt);
        xr[80 + (tid & 15)] = 0;
    }
    if (tid < 384) {   // zero rows 8..15 cols 0..95 (keeps MFMA A-frags finite)
        int r = 8 + tid / 48, c2 = (tid % 48) * 2;
        *(unsigned*)((unsigned short*)(sm + L_X) + r * 104 + c2) = 0u;
    }
    __syncthreads();

    const uint4* W1P = (const uint4*)(wsb + W1P_OFF);
    const uint4* W2P = (const uint4*)(wsb + W2P_OFF);

    // ---- layer 1 MFMA (K=96): wave w -> neurons w*32..w*32+31 ----
    {
        f32x4 a0 = {0.f, 0.f, 0.f, 0.f}, a1 = a0;
        #pragma unroll
        for (int ks = 0; ks < 3; ++ks) {
            U4B8 av; av.u = *(const uint4*)(sm + L_X + (lr * 104 + ks * 32 + g * 8) * 2);
            U4B8 b0; b0.u = W1P[((ks << 4) + t0) * 64 + lane];
            U4B8 b1; b1.u = W1P[((ks << 4) + t0 + 1) * 64 + lane];
            a0 = __builtin_amdgcn_mfma_f32_16x16x32_bf16(av.h, b0.h, a0, 0, 0, 0);
            a1 = __builtin_amdgcn_mfma_f32_16x16x32_bf16(av.h, b1.h, a1, 0, 0, 0);
        }
        const float bn0 = b1g[n0], bn1 = b1g[n1];
        #pragma unroll
        for (int qq = 0; qq < 4; ++qq) {
            *((unsigned short*)(sm + L_H1) + (4 * g + qq) * 264 + n0) =
                bf16rne(fmaxf(a0[qq] + bn0, 0.f));
            *((unsigned short*)(sm + L_H1) + (4 * g + qq) * 264 + n1) =
                bf16rne(fmaxf(a1[qq] + bn1, 0.f));
        }
    }
    __syncthreads();

    // ---- layer 2 MFMA (K=256) ----
    {
        f32x4 a0 = {0.f, 0.f, 0.f, 0.f}, a1 = a0;
        #pragma unroll
        for (int ks = 0; ks < 8; ++ks) {
            U4B8 av; av.u = *(const uint4*)(sm + L_H1 + (lr * 264 + ks * 32 + g * 8) * 2);
            U4B8 b0; b0.u = W2P[((ks << 4) + t0) * 64 + lane];
            U4B8 b1; b1.u = W2P[((ks << 4) + t0 + 1) * 64 + lane];
            a0 = __builtin_amdgcn_mfma_f32_16x16x32_bf16(av.h, b0.h, a0, 0, 0, 0);
            a1 = __builtin_amdgcn_mfma_f32_16x16x32_bf16(av.h, b1.h, a1, 0, 0, 0);
        }
        const float bn0 = b2g[n0], bn1 = b2g[n1];
        #pragma unroll
        for (int qq = 0; qq < 4; ++qq) {
            *((unsigned short*)(sm + L_H2) + (4 * g + qq) * 264 + n0) =
                bf16rne(fmaxf(a0[qq] + bn0, 0.f));
            *((unsigned short*)(sm + L_H2) + (4 * g + qq) * 264 + n1) =
                bf16rne(fmaxf(a1[qq] + bn1, 0.f));
        }
    }
    __syncthreads();

    // ---- heads + finalize: 32 groups of 16 lanes (row m 0..7, output d 0..3) ----
    {
        const int g2 = tid >> 4, m = g2 >> 2, d = g2 & 3, cc = tid & 15;
        const float* wrow = (d < 2) ? (Wmu + d * 256) : (Wls + (d - 2) * 256);
        float hbuf[16];
        uint4 ha = *(const uint4*)(sm + L_H2 + (m * 264 + cc * 16) * 2);
        uint4 hb = *(const uint4*)(sm + L_H2 + (m * 264 + cc * 16 + 8) * 2);
        unpack8(ha, hbuf); unpack8(hb, hbuf + 8);
        float dd = 0.f;
        #pragma unroll
        for (int kk = 0; kk < 16; ++kk)
            dd = fmaf(hbuf[kk], wrow[cc * 16 + kk], dd);
        #pragma unroll
        for (int off = 1; off < 16; off <<= 1) dd += __shfl_xor(dd, off);
        // reuse L_P region (dead) as a tiny [8][4] f32 head buffer
        float* hd = (float*)(sm + L_P);
        if (cc == 0) {
            float bias = (d < 2) ? bmu[d] : bls[d - 2];
            hd[m * 4 + d] = tanhf(dd + bias);
        }
    }
    __syncthreads();
    if (tid < 8) {
        const float* hd = (const float*)(sm + L_P);
        const int m = tid;
        const int orow = b * NT + tile * 8 + m;
        float lp = 0.f;
        #pragma unroll
        for (int d = 0; d < 2; ++d) {
            float mu  = hd[m * 4 + d];
            float lsr = hd[m * 4 + 2 + d];
            float ls  = -20.f + 11.f * (lsr + 1.f);
            float e   = eps[orow * 2 + d];
            float z   = mu + __expf(ls) * e;
            float a   = tanhf(z);
            out[orow * 2 + d] = a;
            lp += -0.5f * e * e - ls - 0.91893853320467274f - __logf(1.f - a * a + 1e-7f);
        }
        out[NB * NT * 2 + orow] = lp;
    }
}

extern "C" void kernel_launch(void* const* d_in, const int* in_sizes, int n_in,
                              void* d_out, int out_size, void* d_ws, size_t ws_size,
                              hipStream_t stream) {
    const float* state = (const float*)d_in[0];
    const float* eps   = (const float*)d_in[1];
    const float* Wq    = (const float*)d_in[2];
    const float* bq    = (const float*)d_in[3];
    const float* Wk    = (const float*)d_in[4];
    const float* bk    = (const float*)d_in[5];
    const float* Wv    = (const float*)d_in[6];
    const float* bv    = (const float*)d_in[7];
    const float* W1    = (const float*)d_in[8];
    const float* b1    = (const float*)d_in[9];
    const float* W2    = (const float*)d_in[10];
    const float* b2    = (const float*)d_in[11];
    const float* Wmu   = (const float*)d_in[12];
    const float* bmu   = (const float*)d_in[13];
    const float* Wls   = (const float*)d_in[14];
    const float* bls   = (const float*)d_in[15];
    float* out = (float*)d_out;
    char* wsb  = (char*)d_ws;

    prep_kernel<<<172, 256, 0, stream>>>(state, Wq, bq, Wk, Wv, W1, W2, wsb);
    actor_kernel<<<512, 512, 0, stream>>>(state, eps, bk, bv, b1, b2,
                                          Wmu, bmu, Wls, bls, wsb, out);
}